// Round 1
// baseline (606.192 us; speedup 1.0000x reference)
//
#include <hip/hip_runtime.h>

// HeavilyCompressedAttention on MI355X (gfx950).
// Pipeline:
//   hs(f32) -> hs_bf(bf16)
//   chunk softmax + entries (f32)                      [k_chunk]
//   ck_lin/cv (small f32 GEMMs)                        [k_small_kv]
//   per-W: transpose+cast W -> Wt(bf16 N-major), MFMA GEMM -> lin(f32),
//          rmsnorm+rope -> bf16 head-major             [k_transpose,k_gemm,k_norm_rope]
//   compressed attn (f32 LDS 3-phase, +sink)           [k_cattn]
//   local windowed attn + merge -> merged_bf           [k_lattn]
//   out GEMM (merged_bf @ Wo_t + bo) -> d_out(f32)     [k_gemm]

typedef unsigned short u16;
typedef __attribute__((ext_vector_type(8))) short short8;
typedef __attribute__((ext_vector_type(4))) float f32x4;

#define S_LEN 2048
#define HIDN  2048
#define NHEAD 16
#define HDIM  128
#define NCHNK 128
#define SCALE 0.08838834764831845f   // 1/sqrt(128)

__device__ __forceinline__ float bf2f(u16 h) {
  return __uint_as_float(((unsigned)h) << 16);
}
__device__ __forceinline__ u16 f2bf(float f) {
  unsigned u = __float_as_uint(f);
  unsigned r = (u + 0x7fffu + ((u >> 16) & 1u)) >> 16;
  return (u16)r;
}
__device__ __forceinline__ float bfu_lo(unsigned u) { return __uint_as_float(u << 16); }
__device__ __forceinline__ float bfu_hi(unsigned u) { return __uint_as_float(u & 0xffff0000u); }

// ---------------- rope table: cos/sin(pos * 10000^(-i/32)), pos<2048, i<32
__global__ __launch_bounds__(256) void k_rope_table(float* __restrict__ rc, float* __restrict__ rs) {
  int i = blockIdx.x * 256 + threadIdx.x;   // 65536 entries
  int pos = i >> 5, f = i & 31;
  // 10000^(-f/32) = exp(-f * ln(10000)/32)
  float inv = __expf(-(float)f * (9.210340371976184f / 32.0f));
  float ang = (float)pos * inv;
  rc[i] = cosf(ang);
  rs[i] = sinf(ang);
}

// ---------------- cast hs f32 -> bf16 (4.19M elems, 4/thread)
__global__ __launch_bounds__(256) void k_cast_hs(const float* __restrict__ src, u16* __restrict__ dst) {
  size_t i4 = ((size_t)blockIdx.x * 256 + threadIdx.x) * 4;
  float4 v = *(const float4*)&src[i4];
  ushort4 o;
  o.x = f2bf(v.x); o.y = f2bf(v.y); o.z = f2bf(v.z); o.w = f2bf(v.w);
  *(ushort4*)&dst[i4] = o;
}

// ---------------- transpose+cast: src f32 (K x N) -> dst bf16 (N x K)
__global__ __launch_bounds__(256) void k_transpose(const float* __restrict__ src, u16* __restrict__ dst,
                                                   int K, int N) {
  __shared__ float tile[32][33];
  int k0 = blockIdx.x * 32, n0 = blockIdx.y * 32;
  int tx = threadIdx.x, ty = threadIdx.y;   // 32 x 8
  #pragma unroll
  for (int i = 0; i < 32; i += 8)
    tile[ty + i][tx] = src[(size_t)(k0 + ty + i) * N + (n0 + tx)];
  __syncthreads();
  #pragma unroll
  for (int i = 0; i < 32; i += 8)
    dst[(size_t)(n0 + ty + i) * K + (k0 + tx)] = f2bf(tile[tx][ty + i]);
}

// ---------------- bf16 MFMA GEMM: C(MxN,f32) = A(MxK) @ Bt(NxK)^T + bias
// 128x128 tile, BK=32, 256 thr (4 waves, 2x2), m97-style linear LDS (conflict-free frags).
__global__ __launch_bounds__(256) void k_gemm(const u16* __restrict__ A, const u16* __restrict__ Bt,
                                              const float* __restrict__ bias, float* __restrict__ C,
                                              int M, int N, int K) {
  __shared__ __align__(16) u16 As[128 * 32];
  __shared__ __align__(16) u16 Bs[128 * 32];
  int tid = threadIdx.x;
  int lane = tid & 63, wave = tid >> 6;
  int wr = wave >> 1, wc = wave & 1;
  int row0 = blockIdx.x * 128, col0 = blockIdx.y * 128;
  f32x4 acc[4][4];
  #pragma unroll
  for (int m = 0; m < 4; ++m)
    #pragma unroll
    for (int n = 0; n < 4; ++n) acc[m][n] = (f32x4){0.f, 0.f, 0.f, 0.f};

  int r0 = tid >> 2;              // 0..63
  int koff = (tid & 3) * 8;       // 0,8,16,24
  int rA = lane & 15, kg = (lane >> 4) * 8;

  for (int k0 = 0; k0 < K; k0 += 32) {
    #pragma unroll
    for (int it = 0; it < 2; ++it) {
      int r = it * 64 + r0;
      *(uint4*)&As[r * 32 + koff] = *(const uint4*)&A[(size_t)(row0 + r) * K + k0 + koff];
      *(uint4*)&Bs[r * 32 + koff] = *(const uint4*)&Bt[(size_t)(col0 + r) * K + k0 + koff];
    }
    __syncthreads();
    short8 af[4], bfr[4];
    #pragma unroll
    for (int m = 0; m < 4; ++m) af[m]  = *(const short8*)&As[(wr * 64 + m * 16 + rA) * 32 + kg];
    #pragma unroll
    for (int n = 0; n < 4; ++n) bfr[n] = *(const short8*)&Bs[(wc * 64 + n * 16 + rA) * 32 + kg];
    #pragma unroll
    for (int m = 0; m < 4; ++m)
      #pragma unroll
      for (int n = 0; n < 4; ++n)
        acc[m][n] = __builtin_amdgcn_mfma_f32_16x16x32_bf16(af[m], bfr[n], acc[m][n], 0, 0, 0);
    __syncthreads();
  }
  // epilogue: C/D layout col=lane&15, row=(lane>>4)*4+j  [guide-verified]
  int rbase = (lane >> 4) * 4, cl = lane & 15;
  #pragma unroll
  for (int m = 0; m < 4; ++m) {
    int rowb = row0 + wr * 64 + m * 16 + rbase;
    #pragma unroll
    for (int n = 0; n < 4; ++n) {
      int col = col0 + wc * 64 + n * 16 + cl;
      float bb = bias ? bias[col] : 0.f;
      #pragma unroll
      for (int j = 0; j < 4; ++j)
        C[(size_t)(rowb + j) * N + col] = acc[m][n][j] + bb;
    }
  }
}

// ---------------- chunk softmax + entries (f32). One block per chunk c.
__global__ __launch_bounds__(256) void k_chunk(const float* __restrict__ hs, const float* __restrict__ Wc,
                                               const float* __restrict__ bc, float* __restrict__ entries) {
  __shared__ float red[16][17];
  __shared__ float wgt[16];
  int c = blockIdx.x, tid = threadIdx.x;
  int r = tid >> 4, seg = tid & 15;
  const float* hrow = hs + ((size_t)c * 16 + r) * HIDN;
  float p = 0.f;
  #pragma unroll 8
  for (int k = seg * 128; k < seg * 128 + 128; k += 4) {
    float4 hv = *(const float4*)&hrow[k];
    float4 wv = *(const float4*)&Wc[k];
    p += hv.x * wv.x + hv.y * wv.y + hv.z * wv.z + hv.w * wv.w;
  }
  red[r][seg] = p;
  __syncthreads();
  if (tid < 16) {
    float lg = 0.f;
    #pragma unroll
    for (int j = 0; j < 16; ++j) lg += red[tid][j];
    lg += bc[0];
    float m = lg;
    #pragma unroll
    for (int msk = 1; msk <= 8; msk <<= 1) m = fmaxf(m, __shfl_xor(m, msk));
    float e = __expf(lg - m);
    float sum = e;
    #pragma unroll
    for (int msk = 1; msk <= 8; msk <<= 1) sum += __shfl_xor(sum, msk);
    wgt[tid] = e / sum;
  }
  __syncthreads();
  for (int hb = tid; hb < HIDN; hb += 256) {
    float acc = 0.f;
    #pragma unroll
    for (int r2 = 0; r2 < 16; ++r2)
      acc += wgt[r2] * hs[((size_t)c * 16 + r2) * HIDN + hb];
    entries[(size_t)c * HIDN + hb] = acc;
  }
}

// ---------------- ck_lin (f32) and cv (bf16): entries(128x2048) @ Wk/Wv(2048x128) + bias
// grid (128, 2): y==0 -> ck_lin, y==1 -> cv_bf. 256 thr = 128 j x 2 k-halves.
__global__ __launch_bounds__(256) void k_small_kv(const float* __restrict__ entries,
                                                  const float* __restrict__ Wk, const float* __restrict__ bk,
                                                  const float* __restrict__ Wv, const float* __restrict__ bv,
                                                  float* __restrict__ ck_lin, u16* __restrict__ cv_bf) {
  __shared__ float red[256];
  int c = blockIdx.x, which = blockIdx.y;
  int tid = threadIdx.x;
  int j = tid & 127, kh = tid >> 7;
  const float* W = which ? Wv : Wk;
  const float* erow = entries + (size_t)c * HIDN;
  float acc = 0.f;
  #pragma unroll 4
  for (int k = kh * 1024; k < kh * 1024 + 1024; ++k)
    acc += erow[k] * W[(size_t)k * HDIM + j];
  red[tid] = acc;
  __syncthreads();
  if (kh == 0) {
    float sum = red[j] + red[j + 128] + (which ? bv[j] : bk[j]);
    if (which) cv_bf[c * HDIM + j] = f2bf(sum);
    else       ck_lin[c * HDIM + j] = sum;
  }
}

// ---------------- rmsnorm + rope on (S, HID=NH*HD) f32 -> (NH, S, HD) bf16. 1 wave per (h,s).
__global__ __launch_bounds__(64) void k_norm_rope(const float* __restrict__ lin, const float* __restrict__ nw,
                                                  const float* __restrict__ rc, const float* __restrict__ rs,
                                                  u16* __restrict__ dst) {
  int b = blockIdx.x;
  int s = b & (S_LEN - 1), h = b >> 11;
  int l = threadIdx.x;
  const float* row = lin + (size_t)s * HIDN + h * HDIM;
  float v0 = row[l], v1 = row[l + 64];
  float ss = v0 * v0 + v1 * v1;
  #pragma unroll
  for (int m = 1; m <= 32; m <<= 1) ss += __shfl_xor(ss, m);
  float rr = rsqrtf(ss * (1.f / 128.f) + 1e-6f);
  float y0 = v0 * rr * nw[l], y1 = v1 * rr * nw[l + 64];
  float pp = __shfl_xor(y0, 32);
  int i = l & 31;
  float cth = rc[s * 32 + i], sth = rs[s * 32 + i];
  float o0 = (l < 32) ? (y0 * cth - pp * sth) : (pp * sth + y0 * cth);
  u16* drow = dst + ((size_t)h * S_LEN + s) * HDIM;
  drow[l] = f2bf(o0);
  drow[l + 64] = f2bf(y1);
}

// ---------------- rmsnorm + rope for ck (128 rows), pos = 16c+15
__global__ __launch_bounds__(64) void k_norm_rope_ck(const float* __restrict__ ck_lin, const float* __restrict__ nw,
                                                     const float* __restrict__ rc, const float* __restrict__ rs,
                                                     u16* __restrict__ dst) {
  int c = blockIdx.x;
  int l = threadIdx.x;
  const float* row = ck_lin + (size_t)c * HDIM;
  float v0 = row[l], v1 = row[l + 64];
  float ss = v0 * v0 + v1 * v1;
  #pragma unroll
  for (int m = 1; m <= 32; m <<= 1) ss += __shfl_xor(ss, m);
  float rr = rsqrtf(ss * (1.f / 128.f) + 1e-6f);
  float y0 = v0 * rr * nw[l], y1 = v1 * rr * nw[l + 64];
  float pp = __shfl_xor(y0, 32);
  int i = l & 31;
  int pos = c * 16 + 15;
  float cth = rc[pos * 32 + i], sth = rs[pos * 32 + i];
  float o0 = (l < 32) ? (y0 * cth - pp * sth) : (pp * sth + y0 * cth);
  u16* drow = dst + (size_t)c * HDIM;
  drow[l] = f2bf(o0);
  drow[l + 64] = f2bf(y1);
}

// ---------------- cast lv lin (S, HID) f32 -> (NH, S, HD) bf16
__global__ __launch_bounds__(256) void k_cast_lv(const float* __restrict__ lin, u16* __restrict__ lv_bf) {
  size_t i4 = ((size_t)blockIdx.x * 256 + threadIdx.x) * 4;
  int d = (int)(i4 & 127);
  size_t rem = i4 >> 7;
  int s = (int)(rem & (S_LEN - 1));
  int h = (int)(rem >> 11);
  float4 v = *(const float4*)&lin[(size_t)s * HIDN + h * HDIM + d];
  ushort4 o;
  o.x = f2bf(v.x); o.y = f2bf(v.y); o.z = f2bf(v.z); o.w = f2bf(v.w);
  *(ushort4*)&lv_bf[i4] = o;
}

// ---------------- compressed attention (+sink) -> ctx_c f32 (NH,S,HD)
// block: 32 queries x 1 head; 3 phases; kv LDS reused for ck then cv.
__global__ __launch_bounds__(256) void k_cattn(const u16* __restrict__ q_bf, const u16* __restrict__ ck_bf,
                                               const u16* __restrict__ cv_bf, const float* __restrict__ sink_k,
                                               const float* __restrict__ sink_v, float* __restrict__ ctx_c) {
  __shared__ __align__(16) float q_lds[32][132];
  __shared__ __align__(16) float sc[32][129];
  __shared__ __align__(16) u16 kv[128 * 128];
  int tid = threadIdx.x;
  int h = blockIdx.y, s0 = blockIdx.x * 32;
  int cmax = s0 / 16 + 2; if (cmax > 128) cmax = 128;
  const size_t hb = (size_t)h * S_LEN * HDIM;

  // stage q (f32)
  for (int i = tid; i < 32 * 32; i += 256) {
    int ql = i >> 5, dz = (i & 31) * 4;
    ushort4 u = *(const ushort4*)&q_bf[hb + (size_t)(s0 + ql) * HDIM + dz];
    q_lds[ql][dz + 0] = bf2f(u.x);
    q_lds[ql][dz + 1] = bf2f(u.y);
    q_lds[ql][dz + 2] = bf2f(u.z);
    q_lds[ql][dz + 3] = bf2f(u.w);
  }
  // stage ck
  for (int i = tid; i < cmax * 16; i += 256) {
    int r = i >> 4, cz = (i & 15) * 8;
    *(uint4*)&kv[r * 128 + cz] = *(const uint4*)&ck_bf[r * 128 + cz];
  }
  __syncthreads();
  { // phase1: scores
    int ql = tid & 31, tsub = tid >> 5;
    int s = s0 + ql;
    for (int c = tsub; c < cmax; c += 8) {
      float acc = 0.f;
      #pragma unroll
      for (int d = 0; d < 128; d += 4) {
        float4 qq = *(const float4*)&q_lds[ql][d];
        uint2 u = *(const uint2*)&kv[c * 128 + d];
        acc += qq.x * bfu_lo(u.x) + qq.y * bfu_hi(u.x)
             + qq.z * bfu_lo(u.y) + qq.w * bfu_hi(u.y);
      }
      bool valid = (c * 16 + 15) <= s;
      sc[ql][c] = valid ? acc * SCALE : -1e9f;
    }
    if (tsub == 0) { // sink score
      float acc = 0.f;
      const float* skr = sink_k + h * HDIM;
      #pragma unroll
      for (int d = 0; d < 128; d += 4) {
        float4 qq = *(const float4*)&q_lds[ql][d];
        float4 kk = *(const float4*)&skr[d];
        acc += qq.x * kk.x + qq.y * kk.y + qq.z * kk.z + qq.w * kk.w;
      }
      sc[ql][cmax] = acc * SCALE;
    }
  }
  __syncthreads();
  // stage cv over kv  (phase1 done reading kv)
  for (int i = tid; i < cmax * 16; i += 256) {
    int r = i >> 4, cz = (i & 15) * 8;
    *(uint4*)&kv[r * 128 + cz] = *(const uint4*)&cv_bf[r * 128 + cz];
  }
  { // phase2: softmax over cmax+1, 8 lanes per query
    int ql = tid >> 3, e = tid & 7;
    int n = cmax + 1;
    float m = -1e30f;
    for (int i = e; i < n; i += 8) m = fmaxf(m, sc[ql][i]);
    m = fmaxf(m, __shfl_xor(m, 1));
    m = fmaxf(m, __shfl_xor(m, 2));
    m = fmaxf(m, __shfl_xor(m, 4));
    float sum = 0.f;
    for (int i = e; i < n; i += 8) {
      float pv = __expf(sc[ql][i] - m);
      sc[ql][i] = pv;
      sum += pv;
    }
    sum += __shfl_xor(sum, 1);
    sum += __shfl_xor(sum, 2);
    sum += __shfl_xor(sum, 4);
    float inv = 1.f / sum;
    for (int i = e; i < n; i += 8) sc[ql][i] *= inv;
  }
  __syncthreads();
  { // phase3: PV + sink_v
    int ql = tid >> 3, e = tid & 7;
    int d0 = e * 16;
    int s = s0 + ql;
    float acc[16];
    float psink = sc[ql][cmax];
    const float* svr = sink_v + h * HDIM + d0;
    #pragma unroll
    for (int j = 0; j < 16; ++j) acc[j] = psink * svr[j];
    for (int c = 0; c < cmax; ++c) {
      float pv = sc[ql][c];
      #pragma unroll
      for (int w = 0; w < 8; ++w) {
        unsigned u = *(const unsigned*)&kv[c * 128 + d0 + 2 * w];
        acc[2 * w]     += pv * bfu_lo(u);
        acc[2 * w + 1] += pv * bfu_hi(u);
      }
    }
    float* orow = ctx_c + hb + (size_t)s * HDIM + d0;
    #pragma unroll
    for (int j = 0; j < 16; j += 4)
      *(float4*)&orow[j] = make_float4(acc[j], acc[j + 1], acc[j + 2], acc[j + 3]);
  }
}

// ---------------- local windowed attention + merge -> merged bf16 (S, NH*HD)
__global__ __launch_bounds__(256) void k_lattn(const u16* __restrict__ q_bf, const u16* __restrict__ lk_bf,
                                               const u16* __restrict__ lv_bf, const float* __restrict__ ctx_c,
                                               u16* __restrict__ merged) {
  __shared__ __align__(16) float q_lds[32][132];
  __shared__ __align__(16) float sc[32][161];
  __shared__ __align__(16) u16 kv[160 * 128];
  int tid = threadIdx.x;
  int h = blockIdx.y, s0 = blockIdx.x * 32;
  int tbase = s0 - 128;
  const size_t hb = (size_t)h * S_LEN * HDIM;

  for (int i = tid; i < 32 * 32; i += 256) {
    int ql = i >> 5, dz = (i & 31) * 4;
    ushort4 u = *(const ushort4*)&q_bf[hb + (size_t)(s0 + ql) * HDIM + dz];
    q_lds[ql][dz + 0] = bf2f(u.x);
    q_lds[ql][dz + 1] = bf2f(u.y);
    q_lds[ql][dz + 2] = bf2f(u.z);
    q_lds[ql][dz + 3] = bf2f(u.w);
  }
  for (int i = tid; i < 160 * 16; i += 256) {
    int r = i >> 4, cz = (i & 15) * 8;
    int t = tbase + r;
    uint4 val = make_uint4(0, 0, 0, 0);
    if (t >= 0) val = *(const uint4*)&lk_bf[hb + (size_t)t * HDIM + cz];
    *(uint4*)&kv[r * 128 + cz] = val;
  }
  __syncthreads();
  { // phase1
    int ql = tid & 31, tsub = tid >> 5;
    int s = s0 + ql;
    for (int r = tsub; r < 160; r += 8) {
      int t = tbase + r;
      float acc = 0.f;
      #pragma unroll
      for (int d = 0; d < 128; d += 4) {
        float4 qq = *(const float4*)&q_lds[ql][d];
        uint2 u = *(const uint2*)&kv[r * 128 + d];
        acc += qq.x * bfu_lo(u.x) + qq.y * bfu_hi(u.x)
             + qq.z * bfu_lo(u.y) + qq.w * bfu_hi(u.y);
      }
      bool valid = (t >= 0) && (t <= s) && (t >= s - 128);
      sc[ql][r] = valid ? acc * SCALE : -1e9f;
    }
  }
  __syncthreads();
  // stage v over kv
  for (int i = tid; i < 160 * 16; i += 256) {
    int r = i >> 4, cz = (i & 15) * 8;
    int t = tbase + r;
    uint4 val = make_uint4(0, 0, 0, 0);
    if (t >= 0) val = *(const uint4*)&lv_bf[hb + (size_t)t * HDIM + cz];
    *(uint4*)&kv[r * 128 + cz] = val;
  }
  { // phase2: softmax over 160
    int ql = tid >> 3, e = tid & 7;
    float m = -1e30f;
    for (int i = e; i < 160; i += 8) m = fmaxf(m, sc[ql][i]);
    m = fmaxf(m, __shfl_xor(m, 1));
    m = fmaxf(m, __shfl_xor(m, 2));
    m = fmaxf(m, __shfl_xor(m, 4));
    float sum = 0.f;
    for (int i = e; i < 160; i += 8) {
      float pv = __expf(sc[ql][i] - m);
      sc[ql][i] = pv;
      sum += pv;
    }
    sum += __shfl_xor(sum, 1);
    sum += __shfl_xor(sum, 2);
    sum += __shfl_xor(sum, 4);
    float inv = 1.f / sum;
    for (int i = e; i < 160; i += 8) sc[ql][i] *= inv;
  }
  __syncthreads();
  { // phase3: PV + merge with ctx_c
    int ql = tid >> 3, e = tid & 7;
    int d0 = e * 16;
    int s = s0 + ql;
    float acc[16];
    #pragma unroll
    for (int j = 0; j < 16; ++j) acc[j] = 0.f;
    for (int r = 0; r < 160; ++r) {
      float pv = sc[ql][r];
      #pragma unroll
      for (int w = 0; w < 8; ++w) {
        unsigned u = *(const unsigned*)&kv[r * 128 + d0 + 2 * w];
        acc[2 * w]     += pv * bfu_lo(u);
        acc[2 * w + 1] += pv * bfu_hi(u);
      }
    }
    const float* crow = ctx_c + hb + (size_t)s * HDIM + d0;
    u16* orow = merged + (size_t)s * HIDN + h * HDIM + d0;
    #pragma unroll
    for (int j = 0; j < 16; j += 4) {
      float4 cc = *(const float4*)&crow[j];
      ushort4 o;
      o.x = f2bf(0.5f * (acc[j + 0] + cc.x));
      o.y = f2bf(0.5f * (acc[j + 1] + cc.y));
      o.z = f2bf(0.5f * (acc[j + 2] + cc.z));
      o.w = f2bf(0.5f * (acc[j + 3] + cc.w));
      *(ushort4*)&orow[j] = o;
    }
  }
}

extern "C" void kernel_launch(void* const* d_in, const int* in_sizes, int n_in,
                              void* d_out, int out_size, void* d_ws, size_t ws_size,
                              hipStream_t stream) {
  const float* hs     = (const float*)d_in[0];
  const float* Wq     = (const float*)d_in[1];
  const float* bq     = (const float*)d_in[2];
  const float* Wc     = (const float*)d_in[3];
  const float* bc     = (const float*)d_in[4];
  const float* Wk     = (const float*)d_in[5];
  const float* bk     = (const float*)d_in[6];
  const float* Wv     = (const float*)d_in[7];
  const float* bv     = (const float*)d_in[8];
  const float* Wlk    = (const float*)d_in[9];
  const float* blk    = (const float*)d_in[10];
  const float* Wlv    = (const float*)d_in[11];
  const float* blv    = (const float*)d_in[12];
  const float* qn_w   = (const float*)d_in[13];
  const float* kn_w   = (const float*)d_in[14];
  const float* sink_k = (const float*)d_in[15];
  const float* sink_v = (const float*)d_in[16];
  const float* Wo     = (const float*)d_in[17];
  const float* bo     = (const float*)d_in[18];
  float* out = (float*)d_out;

  char* p = (char*)d_ws;
  auto alloc = [&](size_t bytes) {
    char* r = p;
    p += (bytes + 255) & ~(size_t)255;
    return r;
  };
  float* rope_c  = (float*)alloc((size_t)S_LEN * 32 * 4);
  float* rope_s  = (float*)alloc((size_t)S_LEN * 32 * 4);
  u16*   hs_bf   = (u16*)  alloc((size_t)S_LEN * HIDN * 2);
  u16*   Wt      = (u16*)  alloc((size_t)HIDN * HIDN * 2);    // reused for each weight
  float* lin     = (float*)alloc((size_t)S_LEN * HIDN * 4);   // reused for q/lk/lv linears
  u16*   q_bf    = (u16*)  alloc((size_t)NHEAD * S_LEN * HDIM * 2);
  u16*   lk_bf   = (u16*)  alloc((size_t)NHEAD * S_LEN * HDIM * 2);
  u16*   lv_bf   = (u16*)  alloc((size_t)NHEAD * S_LEN * HDIM * 2);
  float* entries = (float*)alloc((size_t)NCHNK * HIDN * 4);
  float* ck_lin  = (float*)alloc((size_t)NCHNK * HDIM * 4);
  u16*   ck_bf   = (u16*)  alloc((size_t)NCHNK * HDIM * 2);
  u16*   cv_bf   = (u16*)  alloc((size_t)NCHNK * HDIM * 2);
  float* ctx_c   = (float*)alloc((size_t)NHEAD * S_LEN * HDIM * 4);
  u16*   merged  = (u16*)  alloc((size_t)S_LEN * HIDN * 2);
  (void)ws_size; (void)in_sizes; (void)n_in; (void)out_size;

  dim3 tdim(32, 8);
  dim3 tgrid(HIDN / 32, HIDN / 32);

  k_rope_table<<<256, 256, 0, stream>>>(rope_c, rope_s);
  k_cast_hs<<<4096, 256, 0, stream>>>(hs, hs_bf);

  // chunk path (f32)
  k_chunk<<<NCHNK, 256, 0, stream>>>(hs, Wc, bc, entries);
  k_small_kv<<<dim3(NCHNK, 2), 256, 0, stream>>>(entries, Wk, bk, Wv, bv, ck_lin, cv_bf);
  k_norm_rope_ck<<<NCHNK, 64, 0, stream>>>(ck_lin, kn_w, rope_c, rope_s, ck_bf);

  // q
  k_transpose<<<tgrid, tdim, 0, stream>>>(Wq, Wt, HIDN, HIDN);
  k_gemm<<<dim3(16, 16), 256, 0, stream>>>(hs_bf, Wt, bq, lin, S_LEN, HIDN, HIDN);
  k_norm_rope<<<NHEAD * S_LEN, 64, 0, stream>>>(lin, qn_w, rope_c, rope_s, q_bf);
  // lk
  k_transpose<<<tgrid, tdim, 0, stream>>>(Wlk, Wt, HIDN, HIDN);
  k_gemm<<<dim3(16, 16), 256, 0, stream>>>(hs_bf, Wt, blk, lin, S_LEN, HIDN, HIDN);
  k_norm_rope<<<NHEAD * S_LEN, 64, 0, stream>>>(lin, kn_w, rope_c, rope_s, lk_bf);
  // lv
  k_transpose<<<tgrid, tdim, 0, stream>>>(Wlv, Wt, HIDN, HIDN);
  k_gemm<<<dim3(16, 16), 256, 0, stream>>>(hs_bf, Wt, blv, lin, S_LEN, HIDN, HIDN);
  k_cast_lv<<<4096, 256, 0, stream>>>(lin, lv_bf);

  // attention
  k_cattn<<<dim3(64, NHEAD), 256, 0, stream>>>(q_bf, ck_bf, cv_bf, sink_k, sink_v, ctx_c);
  k_lattn<<<dim3(64, NHEAD), 256, 0, stream>>>(q_bf, lk_bf, lv_bf, ctx_c, merged);

  // output projection
  k_transpose<<<tgrid, tdim, 0, stream>>>(Wo, Wt, HIDN, HIDN);
  k_gemm<<<dim3(16, 16), 256, 0, stream>>>(merged, Wt, bo, out, S_LEN, HIDN, HIDN);
}

// Round 2
// 336.146 us; speedup vs baseline: 1.8034x; 1.8034x over previous
//
#include <hip/hip_runtime.h>

// HeavilyCompressedAttention on MI355X (gfx950). R2:
//  - global_load_lds (16B) staging in all MFMA GEMMs
//  - fused q/lk/lv GEMM (grid 16x16x3) with rmsnorm+rope epilogue (no f32 lin)
//  - MFMA-based compressed + local attention (QK via row frags, PV via out^T = V^T P^T)
//  - sink key/value folded into the compressed-attn K tile / V^T column

typedef unsigned short u16;
typedef __attribute__((ext_vector_type(8))) short short8;
typedef __attribute__((ext_vector_type(4))) float f32x4;

#define S_LEN 2048
#define HIDN  2048
#define NHEAD 16
#define HDIM  128
#define NCHNK 128
#define SCALE 0.08838834764831845f   // 1/sqrt(128)

__device__ __forceinline__ float bf2f(u16 h) {
  return __uint_as_float(((unsigned)h) << 16);
}
__device__ __forceinline__ u16 f2bf(float f) {
  unsigned u = __float_as_uint(f);
  unsigned r = (u + 0x7fffu + ((u >> 16) & 1u)) >> 16;
  return (u16)r;
}

typedef __attribute__((address_space(3))) unsigned int lds_uint;
typedef __attribute__((address_space(1))) unsigned int glb_uint;
__device__ __forceinline__ void gl_lds16(const void* g, void* l) {
  __builtin_amdgcn_global_load_lds((glb_uint*)(unsigned long long)g,
                                   (lds_uint*)(unsigned)(unsigned long long)l,
                                   16, 0, 0);
}

// ---------------- rope table: cos/sin(pos * 10000^(-i/32)), pos<2048, i<32
__global__ __launch_bounds__(256) void k_rope_table(float* __restrict__ rc, float* __restrict__ rs) {
  int i = blockIdx.x * 256 + threadIdx.x;   // 65536 entries
  int pos = i >> 5, f = i & 31;
  float inv = __expf(-(float)f * (9.210340371976184f / 32.0f));
  float ang = (float)pos * inv;
  rc[i] = cosf(ang);
  rs[i] = sinf(ang);
}

// ---------------- cast hs f32 -> bf16
__global__ __launch_bounds__(256) void k_cast_hs(const float* __restrict__ src, u16* __restrict__ dst) {
  size_t i4 = ((size_t)blockIdx.x * 256 + threadIdx.x) * 4;
  float4 v = *(const float4*)&src[i4];
  ushort4 o;
  o.x = f2bf(v.x); o.y = f2bf(v.y); o.z = f2bf(v.z); o.w = f2bf(v.w);
  *(ushort4*)&dst[i4] = o;
}

// ---------------- transpose+cast: src f32 (K x N) -> dst bf16 (N x K)
__global__ __launch_bounds__(256) void k_transpose(const float* __restrict__ src, u16* __restrict__ dst,
                                                   int K, int N) {
  __shared__ float tile[32][33];
  int k0 = blockIdx.x * 32, n0 = blockIdx.y * 32;
  int tx = threadIdx.x, ty = threadIdx.y;   // 32 x 8
  #pragma unroll
  for (int i = 0; i < 32; i += 8)
    tile[ty + i][tx] = src[(size_t)(k0 + ty + i) * N + (n0 + tx)];
  __syncthreads();
  #pragma unroll
  for (int i = 0; i < 32; i += 8)
    dst[(size_t)(n0 + ty + i) * K + (k0 + tx)] = f2bf(tile[tx][ty + i]);
}

// ---------------- chunk softmax + entries (f32). One block per chunk c.
__global__ __launch_bounds__(256) void k_chunk(const float* __restrict__ hs, const float* __restrict__ Wc,
                                               const float* __restrict__ bc, float* __restrict__ entries) {
  __shared__ float red[16][17];
  __shared__ float wgt[16];
  int c = blockIdx.x, tid = threadIdx.x;
  int r = tid >> 4, seg = tid & 15;
  const float* hrow = hs + ((size_t)c * 16 + r) * HIDN;
  float p = 0.f;
  #pragma unroll 8
  for (int k = seg * 128; k < seg * 128 + 128; k += 4) {
    float4 hv = *(const float4*)&hrow[k];
    float4 wv = *(const float4*)&Wc[k];
    p += hv.x * wv.x + hv.y * wv.y + hv.z * wv.z + hv.w * wv.w;
  }
  red[r][seg] = p;
  __syncthreads();
  if (tid < 16) {
    float lg = 0.f;
    #pragma unroll
    for (int j = 0; j < 16; ++j) lg += red[tid][j];
    lg += bc[0];
    float m = lg;
    #pragma unroll
    for (int msk = 1; msk <= 8; msk <<= 1) m = fmaxf(m, __shfl_xor(m, msk));
    float e = __expf(lg - m);
    float sum = e;
    #pragma unroll
    for (int msk = 1; msk <= 8; msk <<= 1) sum += __shfl_xor(sum, msk);
    wgt[tid] = e / sum;
  }
  __syncthreads();
  for (int hb = tid; hb < HIDN; hb += 256) {
    float acc = 0.f;
    #pragma unroll
    for (int r2 = 0; r2 < 16; ++r2)
      acc += wgt[r2] * hs[((size_t)c * 16 + r2) * HIDN + hb];
    entries[(size_t)c * HIDN + hb] = acc;
  }
}

// ---------------- ck_lin (f32) and cv_t (bf16, transposed [d][c])
__global__ __launch_bounds__(256) void k_small_kv(const float* __restrict__ entries,
                                                  const float* __restrict__ Wk, const float* __restrict__ bk,
                                                  const float* __restrict__ Wv, const float* __restrict__ bv,
                                                  float* __restrict__ ck_lin, u16* __restrict__ cv_t) {
  __shared__ float red[256];
  int c = blockIdx.x, which = blockIdx.y;
  int tid = threadIdx.x;
  int j = tid & 127, kh = tid >> 7;
  const float* W = which ? Wv : Wk;
  const float* erow = entries + (size_t)c * HIDN;
  float acc = 0.f;
  #pragma unroll 4
  for (int k = kh * 1024; k < kh * 1024 + 1024; ++k)
    acc += erow[k] * W[(size_t)k * HDIM + j];
  red[tid] = acc;
  __syncthreads();
  if (kh == 0) {
    float sum = red[j] + red[j + 128] + (which ? bv[j] : bk[j]);
    if (which) cv_t[(size_t)j * NCHNK + c] = f2bf(sum);
    else       ck_lin[c * HDIM + j] = sum;
  }
}

// ---------------- rmsnorm + rope for ck (128 rows), pos = 16c+15
__global__ __launch_bounds__(64) void k_norm_rope_ck(const float* __restrict__ ck_lin, const float* __restrict__ nw,
                                                     const float* __restrict__ rc, const float* __restrict__ rs,
                                                     u16* __restrict__ dst) {
  int c = blockIdx.x;
  int l = threadIdx.x;
  const float* row = ck_lin + (size_t)c * HDIM;
  float v0 = row[l], v1 = row[l + 64];
  float ss = v0 * v0 + v1 * v1;
  #pragma unroll
  for (int m = 1; m <= 32; m <<= 1) ss += __shfl_xor(ss, m);
  float rr = rsqrtf(ss * (1.f / 128.f) + 1e-6f);
  float y0 = v0 * rr * nw[l], y1 = v1 * rr * nw[l + 64];
  float pp = __shfl_xor(y0, 32);
  int i = l & 31;
  int pos = c * 16 + 15;
  float cth = rc[pos * 32 + i], sth = rs[pos * 32 + i];
  float o0 = (l < 32) ? (y0 * cth - pp * sth) : (pp * sth + y0 * cth);
  u16* drow = dst + (size_t)c * HDIM;
  drow[l] = f2bf(o0);
  drow[l + 64] = f2bf(y1);
}

// ---------------- fused q/lk/lv GEMM: hs_bf(2048x2048) @ Wt[mode]^T + bias
// 128x128 tile, BK=32, gload_lds staging. Epilogue:
//  mode 0: rmsnorm(qn_w)+rope -> q_bf (h,s,d)
//  mode 1: rmsnorm(kn_w)+rope -> lk_bf (h,s,d)
//  mode 2: cast -> lv_t (h,d,s)
__global__ __launch_bounds__(256) void k_gemm_qkv(
    const u16* __restrict__ A, const u16* __restrict__ Wt3,
    const float* __restrict__ bq, const float* __restrict__ blk, const float* __restrict__ blv,
    const float* __restrict__ qn_w, const float* __restrict__ kn_w,
    const float* __restrict__ rc, const float* __restrict__ rs,
    u16* __restrict__ q_out, u16* __restrict__ lk_out, u16* __restrict__ lv_t) {
  __shared__ __align__(16) char smem[67584];   // staging (16K) then epi 128x132 f32
  u16* As = (u16*)smem;
  u16* Bs = (u16*)(smem + 8192);
  float* epi = (float*)smem;
  int tid = threadIdx.x, lane = tid & 63, wave = tid >> 6;
  int wr = wave >> 1, wc = wave & 1;
  int row0 = blockIdx.x * 128, col0 = blockIdx.y * 128;
  int mode = blockIdx.z;
  const u16* Bt = Wt3 + (size_t)mode * HIDN * HIDN;
  const float* bias = (mode == 0) ? bq : (mode == 1) ? blk : blv;
  f32x4 acc[4][4];
  #pragma unroll
  for (int m = 0; m < 4; ++m)
    #pragma unroll
    for (int n = 0; n < 4; ++n) acc[m][n] = (f32x4){0.f, 0.f, 0.f, 0.f};

  int r0 = tid >> 2, koff = (tid & 3) * 8;
  int rA = lane & 15, kg = (lane >> 4) * 8;

  for (int k0 = 0; k0 < HIDN; k0 += 32) {
    gl_lds16(&A [(size_t)(row0 + r0)      * HIDN + k0 + koff], &As[tid * 8]);
    gl_lds16(&A [(size_t)(row0 + 64 + r0) * HIDN + k0 + koff], &As[2048 + tid * 8]);
    gl_lds16(&Bt[(size_t)(col0 + r0)      * HIDN + k0 + koff], &Bs[tid * 8]);
    gl_lds16(&Bt[(size_t)(col0 + 64 + r0) * HIDN + k0 + koff], &Bs[2048 + tid * 8]);
    __syncthreads();
    short8 af[4], bfv[4];
    #pragma unroll
    for (int m = 0; m < 4; ++m) af[m]  = *(const short8*)&As[(wr * 64 + m * 16 + rA) * 32 + kg];
    #pragma unroll
    for (int n = 0; n < 4; ++n) bfv[n] = *(const short8*)&Bs[(wc * 64 + n * 16 + rA) * 32 + kg];
    #pragma unroll
    for (int m = 0; m < 4; ++m)
      #pragma unroll
      for (int n = 0; n < 4; ++n)
        acc[m][n] = __builtin_amdgcn_mfma_f32_16x16x32_bf16(af[m], bfv[n], acc[m][n], 0, 0, 0);
    __syncthreads();
  }

  int rbase = (lane >> 4) * 4, cl = lane & 15;
  int hh = col0 >> 7;
  if (mode == 2) {
    #pragma unroll
    for (int m = 0; m < 4; ++m) {
      int sb = row0 + wr * 64 + m * 16 + rbase;
      #pragma unroll
      for (int n = 0; n < 4; ++n) {
        int dl = wc * 64 + n * 16 + cl;
        float bb = bias[col0 + dl];
        ushort4 o;
        o.x = f2bf(acc[m][n][0] + bb);
        o.y = f2bf(acc[m][n][1] + bb);
        o.z = f2bf(acc[m][n][2] + bb);
        o.w = f2bf(acc[m][n][3] + bb);
        *(ushort4*)&lv_t[((size_t)hh * HDIM + dl) * S_LEN + sb] = o;
      }
    }
  } else {
    #pragma unroll
    for (int m = 0; m < 4; ++m)
      #pragma unroll
      for (int n = 0; n < 4; ++n) {
        int dl = wc * 64 + n * 16 + cl;
        float bb = bias[col0 + dl];
        #pragma unroll
        for (int j = 0; j < 4; ++j)
          epi[(size_t)(wr * 64 + m * 16 + rbase + j) * 132 + dl] = acc[m][n][j] + bb;
      }
    __syncthreads();
    const float* nw = (mode == 0) ? qn_w : kn_w;
    u16* dstb = (mode == 0) ? q_out : lk_out;
    int r = tid >> 1, half = tid & 1;
    int s = row0 + r;
    float ssum = 0.f;
    int dbase = half * 64;
    #pragma unroll
    for (int d2 = 0; d2 < 64; ++d2) {
      float v = epi[r * 132 + dbase + d2];
      ssum += v * v;
    }
    ssum += __shfl_xor(ssum, 1);
    float rr2 = rsqrtf(ssum * (1.f / 128.f) + 1e-6f);
    u16* dst = dstb + ((size_t)hh * S_LEN + s) * HDIM;
    if (half == 0) {
      #pragma unroll
      for (int i = 0; i < 32; i += 2) {
        float x1a = epi[r * 132 + i] * rr2 * nw[i];
        float x2a = epi[r * 132 + 32 + i] * rr2 * nw[32 + i];
        float x1b = epi[r * 132 + i + 1] * rr2 * nw[i + 1];
        float x2b = epi[r * 132 + 33 + i] * rr2 * nw[33 + i];
        float ca = rc[s * 32 + i], sa = rs[s * 32 + i];
        float cb = rc[s * 32 + i + 1], sb2 = rs[s * 32 + i + 1];
        unsigned lo = (unsigned)f2bf(x1a * ca - x2a * sa) | ((unsigned)f2bf(x1b * cb - x2b * sb2) << 16);
        unsigned hi = (unsigned)f2bf(x1a * sa + x2a * ca) | ((unsigned)f2bf(x1b * sb2 + x2b * cb) << 16);
        *(unsigned*)&dst[i] = lo;
        *(unsigned*)&dst[32 + i] = hi;
      }
    } else {
      #pragma unroll
      for (int i = 0; i < 64; i += 2) {
        unsigned w = (unsigned)f2bf(epi[r * 132 + 64 + i] * rr2 * nw[64 + i])
                   | ((unsigned)f2bf(epi[r * 132 + 65 + i] * rr2 * nw[65 + i]) << 16);
        *(unsigned*)&dst[64 + i] = w;
      }
    }
  }
}

// ---------------- out GEMM: merged(bf16) @ Wt_o^T + bo -> f32 out
__global__ __launch_bounds__(256) void k_gemm_out(const u16* __restrict__ A, const u16* __restrict__ Bt,
                                                  const float* __restrict__ bias, float* __restrict__ C) {
  __shared__ __align__(16) u16 As[128 * 32];
  __shared__ __align__(16) u16 Bs[128 * 32];
  int tid = threadIdx.x, lane = tid & 63, wave = tid >> 6;
  int wr = wave >> 1, wc = wave & 1;
  int row0 = blockIdx.x * 128, col0 = blockIdx.y * 128;
  f32x4 acc[4][4];
  #pragma unroll
  for (int m = 0; m < 4; ++m)
    #pragma unroll
    for (int n = 0; n < 4; ++n) acc[m][n] = (f32x4){0.f, 0.f, 0.f, 0.f};
  int r0 = tid >> 2, koff = (tid & 3) * 8;
  int rA = lane & 15, kg = (lane >> 4) * 8;
  for (int k0 = 0; k0 < HIDN; k0 += 32) {
    gl_lds16(&A [(size_t)(row0 + r0)      * HIDN + k0 + koff], &As[tid * 8]);
    gl_lds16(&A [(size_t)(row0 + 64 + r0) * HIDN + k0 + koff], &As[2048 + tid * 8]);
    gl_lds16(&Bt[(size_t)(col0 + r0)      * HIDN + k0 + koff], &Bs[tid * 8]);
    gl_lds16(&Bt[(size_t)(col0 + 64 + r0) * HIDN + k0 + koff], &Bs[2048 + tid * 8]);
    __syncthreads();
    short8 af[4], bfv[4];
    #pragma unroll
    for (int m = 0; m < 4; ++m) af[m]  = *(const short8*)&As[(wr * 64 + m * 16 + rA) * 32 + kg];
    #pragma unroll
    for (int n = 0; n < 4; ++n) bfv[n] = *(const short8*)&Bs[(wc * 64 + n * 16 + rA) * 32 + kg];
    #pragma unroll
    for (int m = 0; m < 4; ++m)
      #pragma unroll
      for (int n = 0; n < 4; ++n)
        acc[m][n] = __builtin_amdgcn_mfma_f32_16x16x32_bf16(af[m], bfv[n], acc[m][n], 0, 0, 0);
    __syncthreads();
  }
  int rbase = (lane >> 4) * 4, cl = lane & 15;
  #pragma unroll
  for (int m = 0; m < 4; ++m) {
    int rowb = row0 + wr * 64 + m * 16 + rbase;
    #pragma unroll
    for (int n = 0; n < 4; ++n) {
      int col = col0 + wc * 64 + n * 16 + cl;
      float bb = bias[col];
      #pragma unroll
      for (int j = 0; j < 4; ++j)
        C[(size_t)(rowb + j) * HIDN + col] = acc[m][n][j] + bb;
    }
  }
}

// ---------------- compressed attention (MFMA) -> ctx_c f32 (h,s,d). sink folded in.
__global__ __launch_bounds__(256) void k_cattn(const u16* __restrict__ q_bf, const u16* __restrict__ ck_bf,
                                               const u16* __restrict__ cv_t, const float* __restrict__ sink_k,
                                               const float* __restrict__ sink_v, float* __restrict__ ctx_c) {
  __shared__ __align__(16) u16 kv[21760];     // K tile [keys][136] then V^T [128][168]
  __shared__ __align__(16) float sc[32][164];
  __shared__ __align__(16) u16 pb[32][168];
  int tid = threadIdx.x, lane = tid & 63, wave = tid >> 6;
  int h = blockIdx.y, s0 = blockIdx.x * 32;
  int cmax = s0 / 16 + 2; if (cmax > 128) cmax = 128;
  int nkeys = cmax + 1;                        // + sink
  int nkt = (nkeys + 15) >> 4, nkc = (nkeys + 31) >> 5;
  const size_t hb = (size_t)h * S_LEN * HDIM;
  int rA = lane & 15, kg8 = (lane >> 4) * 8;
  int qt = wave & 1, wg = wave >> 1;

  short8 aq[4];
  #pragma unroll
  for (int c = 0; c < 4; ++c)
    aq[c] = *(const short8*)&q_bf[hb + (size_t)(s0 + qt * 16 + rA) * HDIM + c * 32 + kg8];

  for (int i = tid; i < cmax * 16; i += 256) {
    int r = i >> 4, cz = (i & 15) * 8;
    *(uint4*)&kv[r * 136 + cz] = *(const uint4*)&ck_bf[r * HDIM + cz];
  }
  if (tid < 128) kv[cmax * 136 + tid] = f2bf(sink_k[h * HDIM + tid]);
  __syncthreads();

  for (int kt = wg; kt < nkt; kt += 2) {
    f32x4 a = (f32x4){0.f, 0.f, 0.f, 0.f};
    #pragma unroll
    for (int c = 0; c < 4; ++c) {
      short8 bk = *(const short8*)&kv[(kt * 16 + rA) * 136 + c * 32 + kg8];
      a = __builtin_amdgcn_mfma_f32_16x16x32_bf16(aq[c], bk, a, 0, 0, 0);
    }
    int rq = qt * 16 + (lane >> 4) * 4;
    #pragma unroll
    for (int j = 0; j < 4; ++j) sc[rq + j][kt * 16 + rA] = a[j];
  }
  __syncthreads();

  { // softmax (8 lanes / row)
    int ql = tid >> 3, e = tid & 7, s = s0 + ql;
    int NK = nkc * 32;
    float m = -1e30f;
    for (int i = e; i < NK; i += 8) {
      if (i < nkeys) {
        float raw = sc[ql][i];
        bool valid = (i < cmax) ? (i * 16 + 15 <= s) : true;
        float v = valid ? raw * SCALE : -1e9f;
        sc[ql][i] = v;
        m = fmaxf(m, v);
      }
    }
    m = fmaxf(m, __shfl_xor(m, 1));
    m = fmaxf(m, __shfl_xor(m, 2));
    m = fmaxf(m, __shfl_xor(m, 4));
    float sum = 0.f;
    for (int i = e; i < NK; i += 8) {
      if (i < nkeys) {
        float pv = __expf(sc[ql][i] - m);
        sc[ql][i] = pv;
        sum += pv;
      }
    }
    sum += __shfl_xor(sum, 1);
    sum += __shfl_xor(sum, 2);
    sum += __shfl_xor(sum, 4);
    float inv = 1.f / sum;
    for (int i = e; i < NK; i += 8)
      pb[ql][i] = (i < nkeys) ? f2bf(sc[ql][i] * inv) : (u16)0;
  }
  __syncthreads();

  { // stage V^T (d x keys); col cmax = sink_v; beyond = 0
    int d = tid & 127, cstart = tid >> 7;
    u16 sv = f2bf(sink_v[h * HDIM + d]);
    int NC = nkc * 32;
    for (int c = cstart; c < NC; c += 2) {
      u16 v = (c < cmax) ? cv_t[(size_t)d * NCHNK + c] : ((c == cmax) ? sv : (u16)0);
      kv[d * 168 + c] = v;
    }
  }
  __syncthreads();

  { // PV: out^T = V^T . P^T
    f32x4 po[4];
    #pragma unroll
    for (int n = 0; n < 4; ++n) po[n] = (f32x4){0.f, 0.f, 0.f, 0.f};
    for (int kc = 0; kc < nkc; ++kc) {
      short8 pfrag = *(const short8*)&pb[qt * 16 + rA][kc * 32 + kg8];
      #pragma unroll
      for (int n = 0; n < 4; ++n) {
        short8 av = *(const short8*)&kv[(wg * 64 + n * 16 + rA) * 168 + kc * 32 + kg8];
        po[n] = __builtin_amdgcn_mfma_f32_16x16x32_bf16(av, pfrag, po[n], 0, 0, 0);
      }
    }
    int q = qt * 16 + rA;
    int s = s0 + q;
    int rb = (lane >> 4) * 4;
    #pragma unroll
    for (int n = 0; n < 4; ++n) {
      int d0 = wg * 64 + n * 16 + rb;
      *(float4*)&ctx_c[hb + (size_t)s * HDIM + d0] =
          make_float4(po[n][0], po[n][1], po[n][2], po[n][3]);
    }
  }
}

// ---------------- local windowed attention (MFMA) + merge -> merged bf16 (s, h*128+d)
__global__ __launch_bounds__(256) void k_lattn(const u16* __restrict__ q_bf, const u16* __restrict__ lk_bf,
                                               const u16* __restrict__ lv_t, const float* __restrict__ ctx_c,
                                               u16* __restrict__ merged) {
  __shared__ __align__(16) u16 kv[21760];     // K tile [160][136] then V^T [128][168]
  __shared__ __align__(16) float sc[32][164];
  __shared__ __align__(16) u16 pb[32][168];
  int tid = threadIdx.x, lane = tid & 63, wave = tid >> 6;
  int h = blockIdx.y, s0 = blockIdx.x * 32;
  int tbase = s0 - 128;
  const size_t hb = (size_t)h * S_LEN * HDIM;
  int rA = lane & 15, kg8 = (lane >> 4) * 8;
  int qt = wave & 1, wg = wave >> 1;

  short8 aq[4];
  #pragma unroll
  for (int c = 0; c < 4; ++c)
    aq[c] = *(const short8*)&q_bf[hb + (size_t)(s0 + qt * 16 + rA) * HDIM + c * 32 + kg8];

  for (int i = tid; i < 160 * 16; i += 256) {
    int r = i >> 4, cz = (i & 15) * 8;
    int t = tbase + r;
    uint4 val = make_uint4(0, 0, 0, 0);
    if (t >= 0) val = *(const uint4*)&lk_bf[hb + (size_t)t * HDIM + cz];
    *(uint4*)&kv[r * 136 + cz] = val;
  }
  __syncthreads();

  for (int kt = wg; kt < 10; kt += 2) {
    f32x4 a = (f32x4){0.f, 0.f, 0.f, 0.f};
    #pragma unroll
    for (int c = 0; c < 4; ++c) {
      short8 bk = *(const short8*)&kv[(kt * 16 + rA) * 136 + c * 32 + kg8];
      a = __builtin_amdgcn_mfma_f32_16x16x32_bf16(aq[c], bk, a, 0, 0, 0);
    }
    int rq = qt * 16 + (lane >> 4) * 4;
    #pragma unroll
    for (int j = 0; j < 4; ++j) sc[rq + j][kt * 16 + rA] = a[j];
  }
  __syncthreads();

  { // softmax over 160: valid i in [max(ql, 128-s0), ql+128]
    int ql = tid >> 3, e = tid & 7;
    int ilo = 128 - s0; if (ql > ilo) ilo = ql;
    int ihi = ql + 128;
    float m = -1e30f;
    for (int i = e; i < 160; i += 8) {
      bool valid = (i >= ilo) && (i <= ihi);
      float v = valid ? sc[ql][i] * SCALE : -1e9f;
      sc[ql][i] = v;
      m = fmaxf(m, v);
    }
    m = fmaxf(m, __shfl_xor(m, 1));
    m = fmaxf(m, __shfl_xor(m, 2));
    m = fmaxf(m, __shfl_xor(m, 4));
    float sum = 0.f;
    for (int i = e; i < 160; i += 8) {
      float pv = __expf(sc[ql][i] - m);
      sc[ql][i] = pv;
      sum += pv;
    }
    sum += __shfl_xor(sum, 1);
    sum += __shfl_xor(sum, 2);
    sum += __shfl_xor(sum, 4);
    float inv = 1.f / sum;
    for (int i = e; i < 160; i += 8) pb[ql][i] = f2bf(sc[ql][i] * inv);
  }
  __syncthreads();

  { // stage V^T from lv_t (h,d,s)
    int d = tid & 127, c8s = tid >> 7;
    const size_t hbt = (size_t)h * HDIM * S_LEN;
    for (int c8 = c8s; c8 < 20; c8 += 2) {
      int t0 = tbase + c8 * 8;
      uint4 val = make_uint4(0, 0, 0, 0);
      if (t0 >= 0) val = *(const uint4*)&lv_t[hbt + (size_t)d * S_LEN + t0];
      *(uint4*)&kv[d * 168 + c8 * 8] = val;
    }
  }
  __syncthreads();

  { // PV + merge
    f32x4 po[4];
    #pragma unroll
    for (int n = 0; n < 4; ++n) po[n] = (f32x4){0.f, 0.f, 0.f, 0.f};
    #pragma unroll
    for (int kc = 0; kc < 5; ++kc) {
      short8 pfrag = *(const short8*)&pb[qt * 16 + rA][kc * 32 + kg8];
      #pragma unroll
      for (int n = 0; n < 4; ++n) {
        short8 av = *(const short8*)&kv[(wg * 64 + n * 16 + rA) * 168 + kc * 32 + kg8];
        po[n] = __builtin_amdgcn_mfma_f32_16x16x32_bf16(av, pfrag, po[n], 0, 0, 0);
      }
    }
    int q = qt * 16 + rA;
    int s = s0 + q;
    int rb = (lane >> 4) * 4;
    #pragma unroll
    for (int n = 0; n < 4; ++n) {
      int d0 = wg * 64 + n * 16 + rb;
      float4 cc = *(const float4*)&ctx_c[hb + (size_t)s * HDIM + d0];
      ushort4 o;
      o.x = f2bf(0.5f * (po[n][0] + cc.x));
      o.y = f2bf(0.5f * (po[n][1] + cc.y));
      o.z = f2bf(0.5f * (po[n][2] + cc.z));
      o.w = f2bf(0.5f * (po[n][3] + cc.w));
      *(ushort4*)&merged[(size_t)s * HIDN + h * HDIM + d0] = o;
    }
  }
}

extern "C" void kernel_launch(void* const* d_in, const int* in_sizes, int n_in,
                              void* d_out, int out_size, void* d_ws, size_t ws_size,
                              hipStream_t stream) {
  const float* hs     = (const float*)d_in[0];
  const float* Wq     = (const float*)d_in[1];
  const float* bq     = (const float*)d_in[2];
  const float* Wc     = (const float*)d_in[3];
  const float* bc     = (const float*)d_in[4];
  const float* Wk     = (const float*)d_in[5];
  const float* bk     = (const float*)d_in[6];
  const float* Wv     = (const float*)d_in[7];
  const float* bv     = (const float*)d_in[8];
  const float* Wlk    = (const float*)d_in[9];
  const float* blk    = (const float*)d_in[10];
  const float* Wlv    = (const float*)d_in[11];
  const float* blv    = (const float*)d_in[12];
  const float* qn_w   = (const float*)d_in[13];
  const float* kn_w   = (const float*)d_in[14];
  const float* sink_k = (const float*)d_in[15];
  const float* sink_v = (const float*)d_in[16];
  const float* Wo     = (const float*)d_in[17];
  const float* bo     = (const float*)d_in[18];
  float* out = (float*)d_out;

  char* p = (char*)d_ws;
  auto alloc = [&](size_t bytes) {
    char* r = p;
    p += (bytes + 255) & ~(size_t)255;
    return r;
  };
  float* rope_c  = (float*)alloc((size_t)S_LEN * 32 * 4);
  float* rope_s  = (float*)alloc((size_t)S_LEN * 32 * 4);
  u16*   hs_bf   = (u16*)  alloc((size_t)S_LEN * HIDN * 2);
  u16*   Wt3     = (u16*)  alloc((size_t)3 * HIDN * HIDN * 2);
  u16*   Wt_o    = (u16*)  alloc((size_t)HIDN * HIDN * 2);
  u16*   q_bf    = (u16*)  alloc((size_t)NHEAD * S_LEN * HDIM * 2);
  u16*   lk_bf   = (u16*)  alloc((size_t)NHEAD * S_LEN * HDIM * 2);
  u16*   lv_t    = (u16*)  alloc((size_t)NHEAD * HDIM * S_LEN * 2);
  float* entries = (float*)alloc((size_t)NCHNK * HIDN * 4);
  float* ck_lin  = (float*)alloc((size_t)NCHNK * HDIM * 4);
  u16*   ck_bf   = (u16*)  alloc((size_t)NCHNK * HDIM * 2);
  u16*   cv_t    = (u16*)  alloc((size_t)HDIM * NCHNK * 2);
  float* ctx_c   = (float*)alloc((size_t)NHEAD * S_LEN * HDIM * 4);
  u16*   merged  = (u16*)  alloc((size_t)S_LEN * HIDN * 2);
  (void)ws_size; (void)in_sizes; (void)n_in; (void)out_size;

  dim3 tdim(32, 8);
  dim3 tgrid(HIDN / 32, HIDN / 32);

  k_rope_table<<<256, 256, 0, stream>>>(rope_c, rope_s);
  k_cast_hs<<<4096, 256, 0, stream>>>(hs, hs_bf);

  // chunk path
  k_chunk<<<NCHNK, 256, 0, stream>>>(hs, Wc, bc, entries);
  k_small_kv<<<dim3(NCHNK, 2), 256, 0, stream>>>(entries, Wk, bk, Wv, bv, ck_lin, cv_t);
  k_norm_rope_ck<<<NCHNK, 64, 0, stream>>>(ck_lin, kn_w, rope_c, rope_s, ck_bf);

  // weight transposes
  k_transpose<<<tgrid, tdim, 0, stream>>>(Wq,  Wt3,                                   HIDN, HIDN);
  k_transpose<<<tgrid, tdim, 0, stream>>>(Wlk, Wt3 + (size_t)1 * HIDN * HIDN,         HIDN, HIDN);
  k_transpose<<<tgrid, tdim, 0, stream>>>(Wlv, Wt3 + (size_t)2 * HIDN * HIDN,         HIDN, HIDN);
  k_transpose<<<tgrid, tdim, 0, stream>>>(Wo,  Wt_o,                                  HIDN, HIDN);

  // fused q/lk/lv projection + norm/rope epilogues
  k_gemm_qkv<<<dim3(16, 16, 3), 256, 0, stream>>>(hs_bf, Wt3, bq, blk, blv, qn_w, kn_w,
                                                  rope_c, rope_s, q_bf, lk_bf, lv_t);

  // attention
  k_cattn<<<dim3(64, NHEAD), 256, 0, stream>>>(q_bf, ck_bf, cv_t, sink_k, sink_v, ctx_c);
  k_lattn<<<dim3(64, NHEAD), 256, 0, stream>>>(q_bf, lk_bf, lv_t, ctx_c, merged);

  // output projection
  k_gemm_out<<<dim3(16, 16), 256, 0, stream>>>(merged, Wt_o, bo, out);
}

// Round 3
// 278.573 us; speedup vs baseline: 2.1761x; 1.2067x over previous
//
#include <hip/hip_runtime.h>

// HeavilyCompressedAttention on MI355X (gfx950). R3:
//  - k_chunk_kv: fused chunk softmax + entries(LDS) + ck/cv GEMV (8-way k-split)
//    + ck rmsnorm/rope epilogue  (replaces k_chunk, k_small_kv, k_norm_rope_ck)
//  - k_transpose4: all 4 weight transposes in one dispatch
//  - GEMMs/attentions unchanged from R2 (verified)

typedef unsigned short u16;
typedef __attribute__((ext_vector_type(8))) short short8;
typedef __attribute__((ext_vector_type(4))) float f32x4;

#define S_LEN 2048
#define HIDN  2048
#define NHEAD 16
#define HDIM  128
#define NCHNK 128
#define SCALE 0.08838834764831845f   // 1/sqrt(128)

__device__ __forceinline__ float bf2f(u16 h) {
  return __uint_as_float(((unsigned)h) << 16);
}
__device__ __forceinline__ u16 f2bf(float f) {
  unsigned u = __float_as_uint(f);
  unsigned r = (u + 0x7fffu + ((u >> 16) & 1u)) >> 16;
  return (u16)r;
}

typedef __attribute__((address_space(3))) unsigned int lds_uint;
typedef __attribute__((address_space(1))) unsigned int glb_uint;
__device__ __forceinline__ void gl_lds16(const void* g, void* l) {
  __builtin_amdgcn_global_load_lds((glb_uint*)(unsigned long long)g,
                                   (lds_uint*)(unsigned)(unsigned long long)l,
                                   16, 0, 0);
}

// ---------------- rope table: cos/sin(pos * 10000^(-i/32)), pos<2048, i<32
__global__ __launch_bounds__(256) void k_rope_table(float* __restrict__ rc, float* __restrict__ rs) {
  int i = blockIdx.x * 256 + threadIdx.x;   // 65536 entries
  int pos = i >> 5, f = i & 31;
  float inv = __expf(-(float)f * (9.210340371976184f / 32.0f));
  float ang = (float)pos * inv;
  rc[i] = cosf(ang);
  rs[i] = sinf(ang);
}

// ---------------- cast hs f32 -> bf16
__global__ __launch_bounds__(256) void k_cast_hs(const float* __restrict__ src, u16* __restrict__ dst) {
  size_t i4 = ((size_t)blockIdx.x * 256 + threadIdx.x) * 4;
  float4 v = *(const float4*)&src[i4];
  ushort4 o;
  o.x = f2bf(v.x); o.y = f2bf(v.y); o.z = f2bf(v.z); o.w = f2bf(v.w);
  *(ushort4*)&dst[i4] = o;
}

// ---------------- 4 weight transposes in one dispatch: f32 (2048 x 2048) -> bf16 transposed
__global__ __launch_bounds__(256) void k_transpose4(const float* __restrict__ s0, const float* __restrict__ s1,
                                                    const float* __restrict__ s2, const float* __restrict__ s3,
                                                    u16* __restrict__ dqkv, u16* __restrict__ dout) {
  __shared__ float tile[32][33];
  int z = blockIdx.z;
  const float* src = (z == 0) ? s0 : (z == 1) ? s1 : (z == 2) ? s2 : s3;
  u16* dst = (z < 3) ? (dqkv + (size_t)z * HIDN * HIDN) : dout;
  int k0 = blockIdx.x * 32, n0 = blockIdx.y * 32;
  int tx = threadIdx.x, ty = threadIdx.y;   // 32 x 8
  #pragma unroll
  for (int i = 0; i < 32; i += 8)
    tile[ty + i][tx] = src[(size_t)(k0 + ty + i) * HIDN + (n0 + tx)];
  __syncthreads();
  #pragma unroll
  for (int i = 0; i < 32; i += 8)
    dst[(size_t)(n0 + ty + i) * HIDN + (k0 + tx)] = f2bf(tile[tx][ty + i]);
}

// ---------------- fused chunk path: softmax weights -> entries(LDS) -> ck/cv GEMV -> ck norm+rope
// 1 block (1024 thr) per chunk c.
__global__ __launch_bounds__(1024) void k_chunk_kv(
    const float* __restrict__ hs, const float* __restrict__ Wc, const float* __restrict__ bc,
    const float* __restrict__ Wk, const float* __restrict__ bk,
    const float* __restrict__ Wv, const float* __restrict__ bv,
    const float* __restrict__ kn_w, const float* __restrict__ rc, const float* __restrict__ rs,
    u16* __restrict__ ck_bf, u16* __restrict__ cv_t) {
  __shared__ float e[2048];
  __shared__ float redA[16][65];
  __shared__ float wgt[16];
  __shared__ float redk[8][128];
  __shared__ float redv[8][128];
  __shared__ float sck[128];
  __shared__ float ynorm[128];
  __shared__ float ssred;
  int c = blockIdx.x, tid = threadIdx.x;

  // Phase A: chunk logits (16 rows), 64-way k-split each
  {
    int r = tid >> 6, seg = tid & 63;
    const float* hrow = hs + ((size_t)c * 16 + r) * HIDN;
    float p = 0.f;
    #pragma unroll
    for (int k = seg * 32; k < seg * 32 + 32; k += 4) {
      float4 hv = *(const float4*)&hrow[k];
      float4 wv = *(const float4*)&Wc[k];
      p += hv.x * wv.x + hv.y * wv.y + hv.z * wv.z + hv.w * wv.w;
    }
    redA[r][seg] = p;
  }
  __syncthreads();
  if (tid < 16) {
    float lg = 0.f;
    #pragma unroll
    for (int j = 0; j < 64; ++j) lg += redA[tid][j];
    lg += bc[0];
    float m = lg;
    #pragma unroll
    for (int msk = 1; msk <= 8; msk <<= 1) m = fmaxf(m, __shfl_xor(m, msk));
    float ev = __expf(lg - m);
    float sum = ev;
    #pragma unroll
    for (int msk = 1; msk <= 8; msk <<= 1) sum += __shfl_xor(sum, msk);
    wgt[tid] = ev / sum;
  }
  __syncthreads();

  // Phase B: entries -> LDS
  #pragma unroll
  for (int hb = tid; hb < HIDN; hb += 1024) {
    float acc = 0.f;
    #pragma unroll
    for (int r = 0; r < 16; ++r)
      acc += wgt[r] * hs[((size_t)c * 16 + r) * HIDN + hb];
    e[hb] = acc;
  }
  __syncthreads();

  // Phase C: GEMV for both Wk and Wv, 8-way k-split
  {
    int j = tid & 127, kh = tid >> 7;
    float ak = 0.f, av = 0.f;
    #pragma unroll 4
    for (int k = kh * 256; k < kh * 256 + 256; ++k) {
      float ev = e[k];
      ak += ev * Wk[(size_t)k * HDIM + j];
      av += ev * Wv[(size_t)k * HDIM + j];
    }
    redk[kh][j] = ak;
    redv[kh][j] = av;
  }
  __syncthreads();

  // Phase D: reduce, write cv_t, norm+rope ck
  if (tid < 128) {
    float sk = bk[tid], sv = bv[tid];
    #pragma unroll
    for (int i = 0; i < 8; ++i) { sk += redk[i][tid]; sv += redv[i][tid]; }
    cv_t[(size_t)tid * NCHNK + c] = f2bf(sv);
    sck[tid] = sk;
    redk[0][tid] = sk * sk;
  }
  __syncthreads();
  if (tid < 64) {
    float s2 = redk[0][tid] + redk[0][tid + 64];
    #pragma unroll
    for (int msk = 1; msk <= 32; msk <<= 1) s2 += __shfl_xor(s2, msk);
    if (tid == 0) ssred = s2;
  }
  __syncthreads();
  if (tid < 128) {
    float rr = rsqrtf(ssred * (1.f / 128.f) + 1e-6f);
    ynorm[tid] = sck[tid] * rr * kn_w[tid];
  }
  __syncthreads();
  if (tid < 128) {
    int pos = c * 16 + 15;
    float o;
    if (tid < 32) {
      o = ynorm[tid] * rc[pos * 32 + tid] - ynorm[tid + 32] * rs[pos * 32 + tid];
    } else if (tid < 64) {
      int i = tid - 32;
      o = ynorm[i] * rs[pos * 32 + i] + ynorm[tid] * rc[pos * 32 + i];
    } else {
      o = ynorm[tid];
    }
    ck_bf[(size_t)c * HDIM + tid] = f2bf(o);
  }
}

// ---------------- fused q/lk/lv GEMM: hs_bf(2048x2048) @ Wt[mode]^T + bias
__global__ __launch_bounds__(256) void k_gemm_qkv(
    const u16* __restrict__ A, const u16* __restrict__ Wt3,
    const float* __restrict__ bq, const float* __restrict__ blk, const float* __restrict__ blv,
    const float* __restrict__ qn_w, const float* __restrict__ kn_w,
    const float* __restrict__ rc, const float* __restrict__ rs,
    u16* __restrict__ q_out, u16* __restrict__ lk_out, u16* __restrict__ lv_t) {
  __shared__ __align__(16) char smem[67584];   // staging (16K) then epi 128x132 f32
  u16* As = (u16*)smem;
  u16* Bs = (u16*)(smem + 8192);
  float* epi = (float*)smem;
  int tid = threadIdx.x, lane = tid & 63, wave = tid >> 6;
  int wr = wave >> 1, wc = wave & 1;
  int row0 = blockIdx.x * 128, col0 = blockIdx.y * 128;
  int mode = blockIdx.z;
  const u16* Bt = Wt3 + (size_t)mode * HIDN * HIDN;
  const float* bias = (mode == 0) ? bq : (mode == 1) ? blk : blv;
  f32x4 acc[4][4];
  #pragma unroll
  for (int m = 0; m < 4; ++m)
    #pragma unroll
    for (int n = 0; n < 4; ++n) acc[m][n] = (f32x4){0.f, 0.f, 0.f, 0.f};

  int r0 = tid >> 2, koff = (tid & 3) * 8;
  int rA = lane & 15, kg = (lane >> 4) * 8;

  for (int k0 = 0; k0 < HIDN; k0 += 32) {
    gl_lds16(&A [(size_t)(row0 + r0)      * HIDN + k0 + koff], &As[tid * 8]);
    gl_lds16(&A [(size_t)(row0 + 64 + r0) * HIDN + k0 + koff], &As[2048 + tid * 8]);
    gl_lds16(&Bt[(size_t)(col0 + r0)      * HIDN + k0 + koff], &Bs[tid * 8]);
    gl_lds16(&Bt[(size_t)(col0 + 64 + r0) * HIDN + k0 + koff], &Bs[2048 + tid * 8]);
    __syncthreads();
    short8 af[4], bfv[4];
    #pragma unroll
    for (int m = 0; m < 4; ++m) af[m]  = *(const short8*)&As[(wr * 64 + m * 16 + rA) * 32 + kg];
    #pragma unroll
    for (int n = 0; n < 4; ++n) bfv[n] = *(const short8*)&Bs[(wc * 64 + n * 16 + rA) * 32 + kg];
    #pragma unroll
    for (int m = 0; m < 4; ++m)
      #pragma unroll
      for (int n = 0; n < 4; ++n)
        acc[m][n] = __builtin_amdgcn_mfma_f32_16x16x32_bf16(af[m], bfv[n], acc[m][n], 0, 0, 0);
    __syncthreads();
  }

  int rbase = (lane >> 4) * 4, cl = lane & 15;
  int hh = col0 >> 7;
  if (mode == 2) {
    #pragma unroll
    for (int m = 0; m < 4; ++m) {
      int sb = row0 + wr * 64 + m * 16 + rbase;
      #pragma unroll
      for (int n = 0; n < 4; ++n) {
        int dl = wc * 64 + n * 16 + cl;
        float bb = bias[col0 + dl];
        ushort4 o;
        o.x = f2bf(acc[m][n][0] + bb);
        o.y = f2bf(acc[m][n][1] + bb);
        o.z = f2bf(acc[m][n][2] + bb);
        o.w = f2bf(acc[m][n][3] + bb);
        *(ushort4*)&lv_t[((size_t)hh * HDIM + dl) * S_LEN + sb] = o;
      }
    }
  } else {
    #pragma unroll
    for (int m = 0; m < 4; ++m)
      #pragma unroll
      for (int n = 0; n < 4; ++n) {
        int dl = wc * 64 + n * 16 + cl;
        float bb = bias[col0 + dl];
        #pragma unroll
        for (int j = 0; j < 4; ++j)
          epi[(size_t)(wr * 64 + m * 16 + rbase + j) * 132 + dl] = acc[m][n][j] + bb;
      }
    __syncthreads();
    const float* nw = (mode == 0) ? qn_w : kn_w;
    u16* dstb = (mode == 0) ? q_out : lk_out;
    int r = tid >> 1, half = tid & 1;
    int s = row0 + r;
    float ssum = 0.f;
    int dbase = half * 64;
    #pragma unroll
    for (int d2 = 0; d2 < 64; ++d2) {
      float v = epi[r * 132 + dbase + d2];
      ssum += v * v;
    }
    ssum += __shfl_xor(ssum, 1);
    float rr2 = rsqrtf(ssum * (1.f / 128.f) + 1e-6f);
    u16* dst = dstb + ((size_t)hh * S_LEN + s) * HDIM;
    if (half == 0) {
      #pragma unroll
      for (int i = 0; i < 32; i += 2) {
        float x1a = epi[r * 132 + i] * rr2 * nw[i];
        float x2a = epi[r * 132 + 32 + i] * rr2 * nw[32 + i];
        float x1b = epi[r * 132 + i + 1] * rr2 * nw[i + 1];
        float x2b = epi[r * 132 + 33 + i] * rr2 * nw[33 + i];
        float ca = rc[s * 32 + i], sa = rs[s * 32 + i];
        float cb = rc[s * 32 + i + 1], sb2 = rs[s * 32 + i + 1];
        unsigned lo = (unsigned)f2bf(x1a * ca - x2a * sa) | ((unsigned)f2bf(x1b * cb - x2b * sb2) << 16);
        unsigned hi = (unsigned)f2bf(x1a * sa + x2a * ca) | ((unsigned)f2bf(x1b * sb2 + x2b * cb) << 16);
        *(unsigned*)&dst[i] = lo;
        *(unsigned*)&dst[32 + i] = hi;
      }
    } else {
      #pragma unroll
      for (int i = 0; i < 64; i += 2) {
        unsigned w = (unsigned)f2bf(epi[r * 132 + 64 + i] * rr2 * nw[64 + i])
                   | ((unsigned)f2bf(epi[r * 132 + 65 + i] * rr2 * nw[65 + i]) << 16);
        *(unsigned*)&dst[64 + i] = w;
      }
    }
  }
}

// ---------------- out GEMM: merged(bf16) @ Wt_o^T + bo -> f32 out
__global__ __launch_bounds__(256) void k_gemm_out(const u16* __restrict__ A, const u16* __restrict__ Bt,
                                                  const float* __restrict__ bias, float* __restrict__ C) {
  __shared__ __align__(16) u16 As[128 * 32];
  __shared__ __align__(16) u16 Bs[128 * 32];
  int tid = threadIdx.x, lane = tid & 63, wave = tid >> 6;
  int wr = wave >> 1, wc = wave & 1;
  int row0 = blockIdx.x * 128, col0 = blockIdx.y * 128;
  f32x4 acc[4][4];
  #pragma unroll
  for (int m = 0; m < 4; ++m)
    #pragma unroll
    for (int n = 0; n < 4; ++n) acc[m][n] = (f32x4){0.f, 0.f, 0.f, 0.f};
  int r0 = tid >> 2, koff = (tid & 3) * 8;
  int rA = lane & 15, kg = (lane >> 4) * 8;
  for (int k0 = 0; k0 < HIDN; k0 += 32) {
    gl_lds16(&A [(size_t)(row0 + r0)      * HIDN + k0 + koff], &As[tid * 8]);
    gl_lds16(&A [(size_t)(row0 + 64 + r0) * HIDN + k0 + koff], &As[2048 + tid * 8]);
    gl_lds16(&Bt[(size_t)(col0 + r0)      * HIDN + k0 + koff], &Bs[tid * 8]);
    gl_lds16(&Bt[(size_t)(col0 + 64 + r0) * HIDN + k0 + koff], &Bs[2048 + tid * 8]);
    __syncthreads();
    short8 af[4], bfv[4];
    #pragma unroll
    for (int m = 0; m < 4; ++m) af[m]  = *(const short8*)&As[(wr * 64 + m * 16 + rA) * 32 + kg];
    #pragma unroll
    for (int n = 0; n < 4; ++n) bfv[n] = *(const short8*)&Bs[(wc * 64 + n * 16 + rA) * 32 + kg];
    #pragma unroll
    for (int m = 0; m < 4; ++m)
      #pragma unroll
      for (int n = 0; n < 4; ++n)
        acc[m][n] = __builtin_amdgcn_mfma_f32_16x16x32_bf16(af[m], bfv[n], acc[m][n], 0, 0, 0);
    __syncthreads();
  }
  int rbase = (lane >> 4) * 4, cl = lane & 15;
  #pragma unroll
  for (int m = 0; m < 4; ++m) {
    int rowb = row0 + wr * 64 + m * 16 + rbase;
    #pragma unroll
    for (int n = 0; n < 4; ++n) {
      int col = col0 + wc * 64 + n * 16 + cl;
      float bb = bias[col];
      #pragma unroll
      for (int j = 0; j < 4; ++j)
        C[(size_t)(rowb + j) * HIDN + col] = acc[m][n][j] + bb;
    }
  }
}

// ---------------- compressed attention (MFMA) -> ctx_c f32 (h,s,d). sink folded in.
__global__ __launch_bounds__(256) void k_cattn(const u16* __restrict__ q_bf, const u16* __restrict__ ck_bf,
                                               const u16* __restrict__ cv_t, const float* __restrict__ sink_k,
                                               const float* __restrict__ sink_v, float* __restrict__ ctx_c) {
  __shared__ __align__(16) u16 kv[21760];     // K tile [keys][136] then V^T [128][168]
  __shared__ __align__(16) float sc[32][164];
  __shared__ __align__(16) u16 pb[32][168];
  int tid = threadIdx.x, lane = tid & 63, wave = tid >> 6;
  int h = blockIdx.y, s0 = blockIdx.x * 32;
  int cmax = s0 / 16 + 2; if (cmax > 128) cmax = 128;
  int nkeys = cmax + 1;                        // + sink
  int nkt = (nkeys + 15) >> 4, nkc = (nkeys + 31) >> 5;
  const size_t hb = (size_t)h * S_LEN * HDIM;
  int rA = lane & 15, kg8 = (lane >> 4) * 8;
  int qt = wave & 1, wg = wave >> 1;

  short8 aq[4];
  #pragma unroll
  for (int c = 0; c < 4; ++c)
    aq[c] = *(const short8*)&q_bf[hb + (size_t)(s0 + qt * 16 + rA) * HDIM + c * 32 + kg8];

  for (int i = tid; i < cmax * 16; i += 256) {
    int r = i >> 4, cz = (i & 15) * 8;
    *(uint4*)&kv[r * 136 + cz] = *(const uint4*)&ck_bf[r * HDIM + cz];
  }
  if (tid < 128) kv[cmax * 136 + tid] = f2bf(sink_k[h * HDIM + tid]);
  __syncthreads();

  for (int kt = wg; kt < nkt; kt += 2) {
    f32x4 a = (f32x4){0.f, 0.f, 0.f, 0.f};
    #pragma unroll
    for (int c = 0; c < 4; ++c) {
      short8 bk = *(const short8*)&kv[(kt * 16 + rA) * 136 + c * 32 + kg8];
      a = __builtin_amdgcn_mfma_f32_16x16x32_bf16(aq[c], bk, a, 0, 0, 0);
    }
    int rq = qt * 16 + (lane >> 4) * 4;
    #pragma unroll
    for (int j = 0; j < 4; ++j) sc[rq + j][kt * 16 + rA] = a[j];
  }
  __syncthreads();

  { // softmax (8 lanes / row)
    int ql = tid >> 3, e = tid & 7, s = s0 + ql;
    int NK = nkc * 32;
    float m = -1e30f;
    for (int i = e; i < NK; i += 8) {
      if (i < nkeys) {
        float raw = sc[ql][i];
        bool valid = (i < cmax) ? (i * 16 + 15 <= s) : true;
        float v = valid ? raw * SCALE : -1e9f;
        sc[ql][i] = v;
        m = fmaxf(m, v);
      }
    }
    m = fmaxf(m, __shfl_xor(m, 1));
    m = fmaxf(m, __shfl_xor(m, 2));
    m = fmaxf(m, __shfl_xor(m, 4));
    float sum = 0.f;
    for (int i = e; i < NK; i += 8) {
      if (i < nkeys) {
        float pv = __expf(sc[ql][i] - m);
        sc[ql][i] = pv;
        sum += pv;
      }
    }
    sum += __shfl_xor(sum, 1);
    sum += __shfl_xor(sum, 2);
    sum += __shfl_xor(sum, 4);
    float inv = 1.f / sum;
    for (int i = e; i < NK; i += 8)
      pb[ql][i] = (i < nkeys) ? f2bf(sc[ql][i] * inv) : (u16)0;
  }
  __syncthreads();

  { // stage V^T (d x keys); col cmax = sink_v; beyond = 0
    int d = tid & 127, cstart = tid >> 7;
    u16 sv = f2bf(sink_v[h * HDIM + d]);
    int NC = nkc * 32;
    for (int c = cstart; c < NC; c += 2) {
      u16 v = (c < cmax) ? cv_t[(size_t)d * NCHNK + c] : ((c == cmax) ? sv : (u16)0);
      kv[d * 168 + c] = v;
    }
  }
  __syncthreads();

  { // PV: out^T = V^T . P^T
    f32x4 po[4];
    #pragma unroll
    for (int n = 0; n < 4; ++n) po[n] = (f32x4){0.f, 0.f, 0.f, 0.f};
    for (int kc = 0; kc < nkc; ++kc) {
      short8 pfrag = *(const short8*)&pb[qt * 16 + rA][kc * 32 + kg8];
      #pragma unroll
      for (int n = 0; n < 4; ++n) {
        short8 av = *(const short8*)&kv[(wg * 64 + n * 16 + rA) * 168 + kc * 32 + kg8];
        po[n] = __builtin_amdgcn_mfma_f32_16x16x32_bf16(av, pfrag, po[n], 0, 0, 0);
      }
    }
    int q = qt * 16 + rA;
    int s = s0 + q;
    int rb = (lane >> 4) * 4;
    #pragma unroll
    for (int n = 0; n < 4; ++n) {
      int d0 = wg * 64 + n * 16 + rb;
      *(float4*)&ctx_c[hb + (size_t)s * HDIM + d0] =
          make_float4(po[n][0], po[n][1], po[n][2], po[n][3]);
    }
  }
}

// ---------------- local windowed attention (MFMA) + merge -> merged bf16 (s, h*128+d)
__global__ __launch_bounds__(256) void k_lattn(const u16* __restrict__ q_bf, const u16* __restrict__ lk_bf,
                                               const u16* __restrict__ lv_t, const float* __restrict__ ctx_c,
                                               u16* __restrict__ merged) {
  __shared__ __align__(16) u16 kv[21760];     // K tile [160][136] then V^T [128][168]
  __shared__ __align__(16) float sc[32][164];
  __shared__ __align__(16) u16 pb[32][168];
  int tid = threadIdx.x, lane = tid & 63, wave = tid >> 6;
  int h = blockIdx.y, s0 = blockIdx.x * 32;
  int tbase = s0 - 128;
  const size_t hb = (size_t)h * S_LEN * HDIM;
  int rA = lane & 15, kg8 = (lane >> 4) * 8;
  int qt = wave & 1, wg = wave >> 1;

  short8 aq[4];
  #pragma unroll
  for (int c = 0; c < 4; ++c)
    aq[c] = *(const short8*)&q_bf[hb + (size_t)(s0 + qt * 16 + rA) * HDIM + c * 32 + kg8];

  for (int i = tid; i < 160 * 16; i += 256) {
    int r = i >> 4, cz = (i & 15) * 8;
    int t = tbase + r;
    uint4 val = make_uint4(0, 0, 0, 0);
    if (t >= 0) val = *(const uint4*)&lk_bf[hb + (size_t)t * HDIM + cz];
    *(uint4*)&kv[r * 136 + cz] = val;
  }
  __syncthreads();

  for (int kt = wg; kt < 10; kt += 2) {
    f32x4 a = (f32x4){0.f, 0.f, 0.f, 0.f};
    #pragma unroll
    for (int c = 0; c < 4; ++c) {
      short8 bk = *(const short8*)&kv[(kt * 16 + rA) * 136 + c * 32 + kg8];
      a = __builtin_amdgcn_mfma_f32_16x16x32_bf16(aq[c], bk, a, 0, 0, 0);
    }
    int rq = qt * 16 + (lane >> 4) * 4;
    #pragma unroll
    for (int j = 0; j < 4; ++j) sc[rq + j][kt * 16 + rA] = a[j];
  }
  __syncthreads();

  { // softmax over 160: valid i in [max(ql, 128-s0), ql+128]
    int ql = tid >> 3, e = tid & 7;
    int ilo = 128 - s0; if (ql > ilo) ilo = ql;
    int ihi = ql + 128;
    float m = -1e30f;
    for (int i = e; i < 160; i += 8) {
      bool valid = (i >= ilo) && (i <= ihi);
      float v = valid ? sc[ql][i] * SCALE : -1e9f;
      sc[ql][i] = v;
      m = fmaxf(m, v);
    }
    m = fmaxf(m, __shfl_xor(m, 1));
    m = fmaxf(m, __shfl_xor(m, 2));
    m = fmaxf(m, __shfl_xor(m, 4));
    float sum = 0.f;
    for (int i = e; i < 160; i += 8) {
      float pv = __expf(sc[ql][i] - m);
      sc[ql][i] = pv;
      sum += pv;
    }
    sum += __shfl_xor(sum, 1);
    sum += __shfl_xor(sum, 2);
    sum += __shfl_xor(sum, 4);
    float inv = 1.f / sum;
    for (int i = e; i < 160; i += 8) pb[ql][i] = f2bf(sc[ql][i] * inv);
  }
  __syncthreads();

  { // stage V^T from lv_t (h,d,s)
    int d = tid & 127, c8s = tid >> 7;
    const size_t hbt = (size_t)h * HDIM * S_LEN;
    for (int c8 = c8s; c8 < 20; c8 += 2) {
      int t0 = tbase + c8 * 8;
      uint4 val = make_uint4(0, 0, 0, 0);
      if (t0 >= 0) val = *(const uint4*)&lv_t[hbt + (size_t)d * S_LEN + t0];
      *(uint4*)&kv[d * 168 + c8 * 8] = val;
    }
  }
  __syncthreads();

  { // PV + merge
    f32x4 po[4];
    #pragma unroll
    for (int n = 0; n < 4; ++n) po[n] = (f32x4){0.f, 0.f, 0.f, 0.f};
    #pragma unroll
    for (int kc = 0; kc < 5; ++kc) {
      short8 pfrag = *(const short8*)&pb[qt * 16 + rA][kc * 32 + kg8];
      #pragma unroll
      for (int n = 0; n < 4; ++n) {
        short8 av = *(const short8*)&kv[(wg * 64 + n * 16 + rA) * 168 + kc * 32 + kg8];
        po[n] = __builtin_amdgcn_mfma_f32_16x16x32_bf16(av, pfrag, po[n], 0, 0, 0);
      }
    }
    int q = qt * 16 + rA;
    int s = s0 + q;
    int rb = (lane >> 4) * 4;
    #pragma unroll
    for (int n = 0; n < 4; ++n) {
      int d0 = wg * 64 + n * 16 + rb;
      float4 cc = *(const float4*)&ctx_c[hb + (size_t)s * HDIM + d0];
      ushort4 o;
      o.x = f2bf(0.5f * (po[n][0] + cc.x));
      o.y = f2bf(0.5f * (po[n][1] + cc.y));
      o.z = f2bf(0.5f * (po[n][2] + cc.z));
      o.w = f2bf(0.5f * (po[n][3] + cc.w));
      *(ushort4*)&merged[(size_t)s * HIDN + h * HDIM + d0] = o;
    }
  }
}

extern "C" void kernel_launch(void* const* d_in, const int* in_sizes, int n_in,
                              void* d_out, int out_size, void* d_ws, size_t ws_size,
                              hipStream_t stream) {
  const float* hs     = (const float*)d_in[0];
  const float* Wq     = (const float*)d_in[1];
  const float* bq     = (const float*)d_in[2];
  const float* Wc     = (const float*)d_in[3];
  const float* bc     = (const float*)d_in[4];
  const float* Wk     = (const float*)d_in[5];
  const float* bk     = (const float*)d_in[6];
  const float* Wv     = (const float*)d_in[7];
  const float* bv     = (const float*)d_in[8];
  const float* Wlk    = (const float*)d_in[9];
  const float* blk    = (const float*)d_in[10];
  const float* Wlv    = (const float*)d_in[11];
  const float* blv    = (const float*)d_in[12];
  const float* qn_w   = (const float*)d_in[13];
  const float* kn_w   = (const float*)d_in[14];
  const float* sink_k = (const float*)d_in[15];
  const float* sink_v = (const float*)d_in[16];
  const float* Wo     = (const float*)d_in[17];
  const float* bo     = (const float*)d_in[18];
  float* out = (float*)d_out;

  char* p = (char*)d_ws;
  auto alloc = [&](size_t bytes) {
    char* r = p;
    p += (bytes + 255) & ~(size_t)255;
    return r;
  };
  float* rope_c  = (float*)alloc((size_t)S_LEN * 32 * 4);
  float* rope_s  = (float*)alloc((size_t)S_LEN * 32 * 4);
  u16*   hs_bf   = (u16*)  alloc((size_t)S_LEN * HIDN * 2);
  u16*   Wt3     = (u16*)  alloc((size_t)3 * HIDN * HIDN * 2);
  u16*   Wt_o    = (u16*)  alloc((size_t)HIDN * HIDN * 2);
  u16*   q_bf    = (u16*)  alloc((size_t)NHEAD * S_LEN * HDIM * 2);
  u16*   lk_bf   = (u16*)  alloc((size_t)NHEAD * S_LEN * HDIM * 2);
  u16*   lv_t    = (u16*)  alloc((size_t)NHEAD * HDIM * S_LEN * 2);
  u16*   ck_bf   = (u16*)  alloc((size_t)NCHNK * HDIM * 2);
  u16*   cv_t    = (u16*)  alloc((size_t)HDIM * NCHNK * 2);
  float* ctx_c   = (float*)alloc((size_t)NHEAD * S_LEN * HDIM * 4);
  u16*   merged  = (u16*)  alloc((size_t)S_LEN * HIDN * 2);
  (void)ws_size; (void)in_sizes; (void)n_in; (void)out_size;

  k_rope_table<<<256, 256, 0, stream>>>(rope_c, rope_s);
  k_cast_hs<<<4096, 256, 0, stream>>>(hs, hs_bf);

  // fused chunk path (softmax + entries + ck/cv + ck norm/rope)
  k_chunk_kv<<<NCHNK, 1024, 0, stream>>>(hs, Wc, bc, Wk, bk, Wv, bv, kn_w,
                                         rope_c, rope_s, ck_bf, cv_t);

  // all 4 weight transposes in one dispatch
  k_transpose4<<<dim3(64, 64, 4), dim3(32, 8), 0, stream>>>(Wq, Wlk, Wlv, Wo, Wt3, Wt_o);

  // fused q/lk/lv projection + norm/rope epilogues
  k_gemm_qkv<<<dim3(16, 16, 3), 256, 0, stream>>>(hs_bf, Wt3, bq, blk, blv, qn_w, kn_w,
                                                  rope_c, rope_s, q_bf, lk_bf, lv_t);

  // attention
  k_cattn<<<dim3(64, NHEAD), 256, 0, stream>>>(q_bf, ck_bf, cv_t, sink_k, sink_v, ctx_c);
  k_lattn<<<dim3(64, NHEAD), 256, 0, stream>>>(q_bf, lk_bf, lv_t, ctx_c, merged);

  // output projection
  k_gemm_out<<<dim3(16, 16), 256, 0, stream>>>(merged, Wt_o, bo, out);
}